// Round 22
// baseline (119.409 us; speedup 1.0000x reference)
//
#include <hip/hip_runtime.h>
#include <hip/hip_fp16.h>

typedef _Float16 f16x8 __attribute__((ext_vector_type(8)));
typedef _Float16 f16x4 __attribute__((ext_vector_type(4)));
typedef float f32x4 __attribute__((ext_vector_type(4)));
typedef float f32x2 __attribute__((ext_vector_type(2)));

#define NPB 128      // nodes per bucket (dst >> 7)
#define FCHUNK 3072  // edges per fill block (3 per thread @ 1024 threads)
#define SEGCAP 20    // slots per (fill-block, bucket) segment (mean 3.93, P(ovf)~1e-9)
#define CAPL 3584    // LDS csr capacity per bucket (mean 2048+pads, 8sigma safe)
#define STAGECAP 4096 // LDS staging capacity (mean 2048, sigma 45)

// FUSED prep + fill. 1024-thread blocks, roles by blockIdx (fill FIRST so the
// latency-bound fill overlaps the BW-bound x-convert):
//  [0,FGRID): edge fill | [FGRID,+X2): x fp32->{fp16,fp8} | +24 weight frags | last: misc
__global__ __launch_bounds__(1024) void k_prepfill(
    const float4* __restrict__ x4, __half2* __restrict__ xh2,
    unsigned* __restrict__ xq, int n4, int X2,
    const int* __restrict__ src, const int* __restrict__ dst,
    int* __restrict__ cnt, int* __restrict__ packed2, int E, int FGRID,
    const float* __restrict__ We, const float* __restrict__ be,
    const float* __restrict__ Wn, __half* __restrict__ Wfrag, float* __restrict__ c2,
    float* __restrict__ stats, int nbuck, int N) {
  int b = blockIdx.x, t = threadIdx.x;
  if (b < FGRID) {
    int fb = b;
    __shared__ int lh[1024];
    int e0 = fb * FCHUNK;
    int e1 = min(e0 + FCHUNK, E);
    lh[t] = 0;
    __syncthreads();
    int dv[3], sv[3];
#pragma unroll
    for (int i = 0; i < 3; ++i) {
      int e = e0 + t + i * 1024;
      dv[i] = (e < e1) ? dst[e] : -1;
      sv[i] = (e < e1) ? src[e] : 0;      // prefetch src: scatter phase has no global loads
      if (dv[i] >= 0) atomicAdd(&lh[dv[i] >> 7], 1);
    }
    __syncthreads();
    if (t < nbuck) cnt[(size_t)t * FGRID + fb] = lh[t];  // non-atomic count
    lh[t] = 0;  // reuse as local cursor
    __syncthreads();
#pragma unroll
    for (int i = 0; i < 3; ++i) {
      int d = dv[i];
      if (d >= 0) {
        int bk = d >> 7;
        unsigned lp = (unsigned)atomicAdd(&lh[bk], 1);
        if (lp < SEGCAP)
          packed2[((size_t)bk * FGRID + fb) * SEGCAP + lp] = sv[i] | ((d & 127) << 20);
      }
    }
  } else if (b < FGRID + X2) {
    int i = (b - FGRID) * 1024 + t;
    if (i < n4) {
      float4 v = x4[i];
      __half2 a, c;
      a.x = __float2half_rn(v.x); a.y = __float2half_rn(v.y);
      c.x = __float2half_rn(v.z); c.y = __float2half_rn(v.w);
      xh2[2 * i] = a;
      xh2[2 * i + 1] = c;
      int w = __builtin_amdgcn_cvt_pk_fp8_f32(v.x, v.y, 0, false);
      w = __builtin_amdgcn_cvt_pk_fp8_f32(v.z, v.w, w, true);
      xq[i] = (unsigned)w;
    }
  } else if (b < FGRID + X2 + 24) {
    int mb = b - FGRID - X2;
    if (t < 512) {
      int mat = mb >> 3, kk = (mb >> 2) & 1, ct = mb & 3;
      int lane = t >> 3, j = t & 7;
      int k = kk * 32 + ((lane >> 4) & 3) * 8 + j;
      int col = ct * 16 + (lane & 15);
      float v;
      if (mat == 0) {
        v = Wn[k * 64 + col];
      } else if (mat == 1) {
        float a = 0.f;
        for (int m = 0; m < 64; ++m) a += We[k * 64 + m] * Wn[(64 + m) * 64 + col];
        v = a;
      } else {
        float a = 0.f;
        for (int m = 0; m < 64; ++m) a += We[(64 + k) * 64 + m] * Wn[(64 + m) * 64 + col];
        v = a;
      }
      Wfrag[mb * 512 + t] = __float2half_rn(v);
    }
  } else {
    if (t < 64) {
      float a = 0.f;
      for (int m = 0; m < 64; ++m) a += be[m] * Wn[(64 + m) * 64 + t];
      c2[t] = a;
    } else if (t < 96) {
      __half2 z; z.x = __float2half_rn(0.f); z.y = __float2half_rn(0.f);
      xh2[(size_t)N * 32 + (t - 64)] = z;   // zero fp16 row N
    } else if (t < 112) {
      xq[(size_t)N * 16 + (t - 96)] = 0u;   // zero fp8 row N (pad target)
    } else if (t >= 128 && t < 256) {
      stats[t - 128] = 0.f;
    }
  }
}

// one 8-edge batch: 8 LDS csr reads (broadcast), slot-select 2 edges,
// 2 dword fp8 gathers (4 feats each), HW cvt, f32 accumulate.
#define LBATCH8(J0, J, AL, AH)                                                 \
  {                                                                            \
    int u_ = (J0) + (J);                                                       \
    int e0_ = csrL[u_ + 0], e1_ = csrL[u_ + 1], e2_ = csrL[u_ + 2], e3_ = csrL[u_ + 3]; \
    int e4_ = csrL[u_ + 4], e5_ = csrL[u_ + 5], e6_ = csrL[u_ + 6], e7_ = csrL[u_ + 7]; \
    int p1_ = (slot & 1) ? e1_ : e0_, q1_ = (slot & 1) ? e3_ : e2_;            \
    int s1_ = (slot & 2) ? q1_ : p1_;                                          \
    int p2_ = (slot & 1) ? e5_ : e4_, q2_ = (slot & 1) ? e7_ : e6_;            \
    int s2_ = (slot & 2) ? q2_ : p2_;                                          \
    unsigned w1_ = xq[((unsigned)s1_ << 4) | q];                               \
    unsigned w2_ = xq[((unsigned)s2_ << 4) | q];                               \
    f32x2 l1_ = __builtin_amdgcn_cvt_pk_f32_fp8(w1_, false);                   \
    f32x2 h1_ = __builtin_amdgcn_cvt_pk_f32_fp8(w1_, true);                    \
    f32x2 l2_ = __builtin_amdgcn_cvt_pk_f32_fp8(w2_, false);                   \
    f32x2 h2_ = __builtin_amdgcn_cvt_pk_f32_fp8(w2_, true);                    \
    AL += l1_; AH += h1_; AL += l2_; AH += h2_;                                \
  }

// FUSED counting sort (CSR in LDS) + aggregation. SINGLE global pass:
// segments -> LDS stage (+hist) -> scan -> LDS scatter -> aggregate.
__global__ __launch_bounds__(512) void k_sortagg(
    const int* __restrict__ packed2, const int* __restrict__ cnt,
    const unsigned* __restrict__ xq, int* __restrict__ deg,
    __half* __restrict__ Sh, int FGRID, int N) {
  __shared__ int scnt[528];
  __shared__ int hist[NPB];
  __shared__ int sc[NPB];
  __shared__ int curs[NPB];
  __shared__ int stage[STAGECAP];
  __shared__ int csrL[CAPL];
  __shared__ int nstage_;
  int b = blockIdx.x, t = threadIdx.x;
  if (t < NPB) hist[t] = 0;
  if (t == 0) nstage_ = 0;
  for (int i = t; i < FGRID; i += 512) scnt[i] = cnt[(size_t)b * FGRID + i];
  __syncthreads();
  int slots = FGRID * SEGCAP;
  const int* seg = packed2 + (size_t)b * FGRID * SEGCAP;
  for (int idx = t; idx < slots; idx += 512) {
    int s = idx / SEGCAP, k = idx - s * SEGCAP;
    if (k < scnt[s]) {
      int pk = seg[idx];
      int p = atomicAdd(&nstage_, 1);
      if (p < STAGECAP) {
        stage[p] = pk;
        atomicAdd(&hist[(pk >> 20) & 127], 1);
      }
    }
  }
  __syncthreads();
  int v = (t < NPB) ? hist[t] : 0;
  int pv = (v + 7) & ~7;       // padded degree
  if (t < NPB) sc[t] = pv;
  __syncthreads();
  for (int d = 1; d < NPB; d <<= 1) {
    int a = (t >= d && t < NPB) ? sc[t - d] : 0;
    __syncthreads();
    if (t < NPB) sc[t] += a;
    __syncthreads();
  }
  if (t < NPB) {
    int ex = sc[t] - pv;       // local CSR start
    curs[t] = ex;
    int n = b * NPB + t;
    if (n < N) deg[n] = v;
    for (int k = v; k < pv; ++k) csrL[ex + k] = N;  // pads -> zero row
  }
  __syncthreads();
  int tot = nstage_ < STAGECAP ? nstage_ : STAGECAP;
  for (int idx = t; idx < tot; idx += 512) {
    int pk = stage[idx];
    int p = atomicAdd(&curs[(pk >> 20) & 127], 1);
    csrL[p] = pk & 0xFFFFF;
  }
  __syncthreads();
  // ---- aggregation: wave w owns local nodes [w*16, w*16+16), dual-interleaved
  int w = t >> 6;
  unsigned lane = t & 63;
  unsigned q = lane & 15;          // feature quad
  int slot = (int)(lane >> 4);     // 0..3
  for (int p = 0; p < 16; p += 2) {
    int ln = w * 16 + p;
    int vA = hist[ln], vB = hist[ln + 1];
    int pdA = (vA + 7) & ~7, pdB = (vB + 7) & ~7;
    int j0A = sc[ln] - pdA, j0B = sc[ln + 1] - pdB;
    f32x2 aAL = {0.f, 0.f}, aAH = {0.f, 0.f};
    f32x2 aBL = {0.f, 0.f}, aBH = {0.f, 0.f};
    int jA = 0, jB = 0;
    for (; jA < pdA && jB < pdB; jA += 8, jB += 8) {
      LBATCH8(j0A, jA, aAL, aAH)
      LBATCH8(j0B, jB, aBL, aBH)
    }
    for (; jA < pdA; jA += 8) LBATCH8(j0A, jA, aAL, aAH)
    for (; jB < pdB; jB += 8) LBATCH8(j0B, jB, aBL, aBH)
    aAL.x += __shfl_xor(aAL.x, 16); aAL.y += __shfl_xor(aAL.y, 16);
    aAH.x += __shfl_xor(aAH.x, 16); aAH.y += __shfl_xor(aAH.y, 16);
    aAL.x += __shfl_xor(aAL.x, 32); aAL.y += __shfl_xor(aAL.y, 32);
    aAH.x += __shfl_xor(aAH.x, 32); aAH.y += __shfl_xor(aAH.y, 32);
    aBL.x += __shfl_xor(aBL.x, 16); aBL.y += __shfl_xor(aBL.y, 16);
    aBH.x += __shfl_xor(aBH.x, 16); aBH.y += __shfl_xor(aBH.y, 16);
    aBL.x += __shfl_xor(aBL.x, 32); aBL.y += __shfl_xor(aBL.y, 32);
    aBH.x += __shfl_xor(aBH.x, 32); aBH.y += __shfl_xor(aBH.y, 32);
    int n = b * NPB + ln;
    if (slot == 0) {
      if (n < N) {
        f16x4 o;
        o[0] = (_Float16)aAL.x; o[1] = (_Float16)aAL.y;
        o[2] = (_Float16)aAH.x; o[3] = (_Float16)aAH.y;
        *(f16x4*)(Sh + ((size_t)n << 6) + (q << 2)) = o;
      }
      if (n + 1 < N) {
        f16x4 o;
        o[0] = (_Float16)aBL.x; o[1] = (_Float16)aBL.y;
        o[2] = (_Float16)aBH.x; o[3] = (_Float16)aBH.y;
        *(f16x4*)(Sh + ((size_t)(n + 1) << 6) + (q << 2)) = o;
      }
    }
  }
}

// node model via MFMA + per-block stats partials (LDS reduce, non-atomic global write)
__global__ __launch_bounds__(256) void k_nodeM(const __half* __restrict__ xh,
    const __half* __restrict__ Sh, const int* __restrict__ deg,
    const __half* __restrict__ Wfrag, const float* __restrict__ c2,
    const float* __restrict__ bnode, const float* __restrict__ pa,
    __half* __restrict__ Hh, float* __restrict__ pstats, int N) {
  __shared__ float ls[128];
  const f16x8* WF = (const f16x8*)Wfrag;
  int t = threadIdx.x, lane = t & 63;
  if (t < 128) ls[t] = 0.f;
  f16x8 B[24];
#pragma unroll
  for (int f = 0; f < 24; ++f) B[f] = WF[f * 64 + lane];
  float slope = pa[0];
  int wid = (blockIdx.x * blockDim.x + t) >> 6;
  int nw = (gridDim.x * blockDim.x) >> 6;
  int ntile = N >> 4;
  int r = lane & 15, g = lane >> 4;
  float ws[4] = {0, 0, 0, 0}, wq[4] = {0, 0, 0, 0};
  __syncthreads();
  for (int tile = wid; tile < ntile; tile += nw) {
    int n0 = tile << 4;
    float dg[4];
#pragma unroll
    for (int qq = 0; qq < 4; ++qq) dg[qq] = (float)deg[n0 + g * 4 + qq];
    const f16x8* xp = (const f16x8*)(xh + (size_t)(n0 + r) * 64 + g * 8);
    const f16x8* sp = (const f16x8*)(Sh + (size_t)(n0 + r) * 64 + g * 8);
    f16x8 ax0 = xp[0], ax1 = xp[4];
    f16x8 as0 = sp[0], as1 = sp[4];
    f32x4 accA[4], accB[4];
#pragma unroll
    for (int ct = 0; ct < 4; ++ct) {
      f32x4 a = {0.f, 0.f, 0.f, 0.f};
      a = __builtin_amdgcn_mfma_f32_16x16x32_f16(ax0, B[0 + ct], a, 0, 0, 0);
      a = __builtin_amdgcn_mfma_f32_16x16x32_f16(ax1, B[4 + ct], a, 0, 0, 0);
      a = __builtin_amdgcn_mfma_f32_16x16x32_f16(as0, B[8 + ct], a, 0, 0, 0);
      a = __builtin_amdgcn_mfma_f32_16x16x32_f16(as1, B[12 + ct], a, 0, 0, 0);
      accA[ct] = a;
      f32x4 bb = {0.f, 0.f, 0.f, 0.f};
      bb = __builtin_amdgcn_mfma_f32_16x16x32_f16(ax0, B[16 + ct], bb, 0, 0, 0);
      bb = __builtin_amdgcn_mfma_f32_16x16x32_f16(ax1, B[20 + ct], bb, 0, 0, 0);
      accB[ct] = bb;
    }
#pragma unroll
    for (int ct = 0; ct < 4; ++ct) {
      int c = ct * 16 + r;
      float cc = c2[c], bv = bnode[c];
#pragma unroll
      for (int qq = 0; qq < 4; ++qq) {
        float hv = accA[ct][qq] + dg[qq] * (accB[ct][qq] + cc) + bv;
        hv = hv >= 0.f ? hv : slope * hv;
        ws[ct] += hv; wq[ct] += hv * hv;
        Hh[(size_t)(n0 + g * 4 + qq) * 64 + c] = __float2half_rn(hv);
      }
    }
  }
#pragma unroll
  for (int ct = 0; ct < 4; ++ct) {
    int c = ct * 16 + r;
    atomicAdd(&ls[c], ws[ct]);
    atomicAdd(&ls[64 + c], wq[ct]);
  }
  __syncthreads();
  if (t < 128) pstats[(size_t)blockIdx.x * 128 + t] = ls[t];
}

// reduce per-block partials (nb x 128) -> stats[128]
__global__ __launch_bounds__(256) void k_stats(const float* __restrict__ pstats,
    float* __restrict__ stats, int nb) {
  int t = threadIdx.x;
  int col = t & 127;
  int half = t >> 7;  // 0/1
  float acc = 0.f;
  for (int i = blockIdx.x * 2 + half; i < nb; i += gridDim.x * 2)
    acc += pstats[(size_t)i * 128 + col];
  atomicAdd(&stats[col], acc);
}

// BN finalize fused into the output pass
__global__ void k_out2(const __half2* __restrict__ hh, const float* __restrict__ stats,
                       const float* __restrict__ gamma, const float* __restrict__ beta,
                       float2* __restrict__ out2, int n2, float invN) {
  int i = blockIdx.x * blockDim.x + threadIdx.x;
  if (i < n2) {
    int cb = (i & 31) * 2;
    float m0 = stats[cb] * invN, m1 = stats[cb + 1] * invN;
    float v0 = stats[64 + cb] * invN - m0 * m0;
    float v1 = stats[64 + cb + 1] * invN - m1 * m1;
    float sc0 = gamma[cb] * rsqrtf(v0 + 1e-5f);
    float sc1 = gamma[cb + 1] * rsqrtf(v1 + 1e-5f);
    float sh0 = beta[cb] - m0 * sc0;
    float sh1 = beta[cb + 1] - m1 * sc1;
    __half2 v = hh[i];
    float2 o;
    o.x = __half2float(v.x) * sc0 + sh0;
    o.y = __half2float(v.y) * sc1 + sh1;
    out2[i] = o;
  }
}

// ---------------- launch ----------------

extern "C" void kernel_launch(void* const* d_in, const int* in_sizes, int n_in,
                              void* d_out, int out_size, void* d_ws, size_t ws_size,
                              hipStream_t stream) {
  const float* x     = (const float*)d_in[0];
  const int*   ei    = (const int*)d_in[1];
  const float* We    = (const float*)d_in[2];
  const float* be    = (const float*)d_in[3];
  const float* Wn    = (const float*)d_in[4];
  const float* bnode = (const float*)d_in[5];
  const float* pa    = (const float*)d_in[6];
  const float* gamma = (const float*)d_in[7];
  const float* beta  = (const float*)d_in[8];

  int N = in_sizes[0] / 64;
  int E = in_sizes[1] / 2;
  const int* srcA = ei;
  const int* dstA = ei + E;

  int NBUCK = (N + NPB - 1) / NPB;         // 782
  int FGRID = (E + FCHUNK - 1) / FCHUNK;   // 521 -> 521*3072 >= E? 521*3072=1600512 >= 1.6e6 ok

  char* ws = (char*)d_ws;
  size_t off = 0;
  auto alloc = [&](size_t bytes) -> void* {
    void* p = (void*)(ws + off);
    off += (bytes + 255) & ~(size_t)255;
    return p;
  };
  int ntile = N / 16;                       // 6250
  int mgrid = (ntile + 3) / 4;              // 1563 blocks -> 1 tile per wave

  float*    stats   = (float*)alloc(128 * 4);
  int*      cnt     = (int*)alloc((size_t)NBUCK * FGRID * 4);
  int*      packed2 = (int*)alloc((size_t)NBUCK * FGRID * SEGCAP * 4);  // ~33 MB
  int*      deg     = (int*)alloc((size_t)N * 4);
  __half*   xh      = (__half*)alloc((size_t)(N + 1) * 64 * 2);  // +1 zero row
  unsigned* xq      = (unsigned*)alloc((size_t)(N + 1) * 64);    // fp8 table +1 zero row
  __half*   Sh      = (__half*)alloc((size_t)N * 64 * 2);
  __half*   Hh      = (__half*)alloc((size_t)N * 64 * 2);
  __half*   Wfrag   = (__half*)alloc((size_t)24 * 512 * 2);
  float*    c2      = (float*)alloc(64 * 4);
  float*    pstats  = (float*)alloc((size_t)mgrid * 128 * 4);

  int n4 = N * 16;
  int X2 = (n4 + 1023) / 1024;             // 1563
  int n2 = N * 32;
  int pgrid = FGRID + X2 + 25;

  k_prepfill<<<pgrid, 1024, 0, stream>>>(
      (const float4*)x, (__half2*)xh, xq, n4, X2,
      srcA, dstA, cnt, packed2, E, FGRID,
      We, be, Wn, Wfrag, c2, stats, NBUCK, N);
  k_sortagg<<<NBUCK, 512, 0, stream>>>(packed2, cnt, xq, deg, Sh, FGRID, N);
  k_nodeM<<<mgrid, 256, 0, stream>>>(xh, Sh, deg, Wfrag, c2, bnode, pa, Hh, pstats, N);
  k_stats<<<64, 256, 0, stream>>>(pstats, stats, mgrid);
  k_out2<<<(n2 + 255) / 256, 256, 0, stream>>>((const __half2*)Hh, stats, gamma, beta,
                                               (float2*)d_out, n2, 1.0f / (float)N);
}

// Round 23
// 111.663 us; speedup vs baseline: 1.0694x; 1.0694x over previous
//
#include <hip/hip_runtime.h>
#include <hip/hip_fp16.h>

typedef _Float16 f16x8 __attribute__((ext_vector_type(8)));
typedef _Float16 f16x4 __attribute__((ext_vector_type(4)));
typedef float f32x4 __attribute__((ext_vector_type(4)));
typedef float f32x2 __attribute__((ext_vector_type(2)));

#define NPB 128      // nodes per bucket (dst >> 7)
#define FCHUNK 6144  // edges per fill block (6 per thread @ 1024 threads)
#define SEGCAP 32    // slots per (fill-block, bucket) segment (mean 7.9, +8.6sigma<32)
#define CAPL 3584    // LDS csr capacity per bucket (mean 2048+pads, 8sigma safe)
#define STAGECAP 4096 // LDS staging capacity (mean 2048, sigma 45)

// FUSED prep + fill. 1024-thread blocks, roles by blockIdx — FILL FIRST so its
// latency-bound blocks co-reside with BW-bound convert blocks (no fill tail):
//  [0,FGRID): edge fill | [FGRID,+X2): x fp32->{fp16,fp8} | +24 wfrag | last: misc
__global__ __launch_bounds__(1024) void k_prepfill(
    const float4* __restrict__ x4, __half2* __restrict__ xh2,
    unsigned* __restrict__ xq, int n4, int X2,
    const int* __restrict__ src, const int* __restrict__ dst,
    int* __restrict__ cnt, int* __restrict__ packed2, int E, int FGRID,
    const float* __restrict__ We, const float* __restrict__ be,
    const float* __restrict__ Wn, __half* __restrict__ Wfrag, float* __restrict__ c2,
    float* __restrict__ stats, int nbuck, int N) {
  int b = blockIdx.x, t = threadIdx.x;
  if (b < FGRID) {
    int fb = b;
    __shared__ int lh[1024];
    int e0 = fb * FCHUNK;
    int e1 = min(e0 + FCHUNK, E);
    lh[t] = 0;
    __syncthreads();
    int dv[6];
#pragma unroll
    for (int i = 0; i < 6; ++i) {
      int e = e0 + t + i * 1024;
      dv[i] = (e < e1) ? dst[e] : -1;
      if (dv[i] >= 0) atomicAdd(&lh[dv[i] >> 7], 1);
    }
    __syncthreads();
    if (t < nbuck) cnt[(size_t)t * FGRID + fb] = lh[t];  // non-atomic count
    lh[t] = 0;  // reuse as local cursor
    __syncthreads();
#pragma unroll
    for (int i = 0; i < 6; ++i) {
      int d = dv[i];
      if (d >= 0) {
        int e = e0 + t + i * 1024;
        int bk = d >> 7;
        unsigned lp = (unsigned)atomicAdd(&lh[bk], 1);
        if (lp < SEGCAP)
          packed2[((size_t)bk * FGRID + fb) * SEGCAP + lp] = src[e] | ((d & 127) << 20);
      }
    }
  } else if (b < FGRID + X2) {
    int i = (b - FGRID) * 1024 + t;
    if (i < n4) {
      float4 v = x4[i];
      __half2 a, c;
      a.x = __float2half_rn(v.x); a.y = __float2half_rn(v.y);
      c.x = __float2half_rn(v.z); c.y = __float2half_rn(v.w);
      xh2[2 * i] = a;
      xh2[2 * i + 1] = c;
      int w = __builtin_amdgcn_cvt_pk_fp8_f32(v.x, v.y, 0, false);
      w = __builtin_amdgcn_cvt_pk_fp8_f32(v.z, v.w, w, true);
      xq[i] = (unsigned)w;
    }
  } else if (b < FGRID + X2 + 24) {
    int mb = b - FGRID - X2;
    if (t < 512) {
      int mat = mb >> 3, kk = (mb >> 2) & 1, ct = mb & 3;
      int lane = t >> 3, j = t & 7;
      int k = kk * 32 + ((lane >> 4) & 3) * 8 + j;
      int col = ct * 16 + (lane & 15);
      float v;
      if (mat == 0) {
        v = Wn[k * 64 + col];
      } else if (mat == 1) {
        float a = 0.f;
        for (int m = 0; m < 64; ++m) a += We[k * 64 + m] * Wn[(64 + m) * 64 + col];
        v = a;
      } else {
        float a = 0.f;
        for (int m = 0; m < 64; ++m) a += We[(64 + k) * 64 + m] * Wn[(64 + m) * 64 + col];
        v = a;
      }
      Wfrag[mb * 512 + t] = __float2half_rn(v);
    }
  } else {
    if (t < 64) {
      float a = 0.f;
      for (int m = 0; m < 64; ++m) a += be[m] * Wn[(64 + m) * 64 + t];
      c2[t] = a;
    } else if (t < 96) {
      __half2 z; z.x = __float2half_rn(0.f); z.y = __float2half_rn(0.f);
      xh2[(size_t)N * 32 + (t - 64)] = z;   // zero fp16 row N
    } else if (t < 112) {
      xq[(size_t)N * 16 + (t - 96)] = 0u;   // zero fp8 row N (pad target)
    } else if (t >= 128 && t < 256) {
      stats[t - 128] = 0.f;
    }
  }
}

// one 8-edge batch: 8 LDS csr reads (broadcast), slot-select 2 edges,
// 2 dword fp8 gathers (4 feats each), HW cvt, f32 accumulate.
#define LBATCH8(J0, J, AL, AH)                                                 \
  {                                                                            \
    int u_ = (J0) + (J);                                                       \
    int e0_ = csrL[u_ + 0], e1_ = csrL[u_ + 1], e2_ = csrL[u_ + 2], e3_ = csrL[u_ + 3]; \
    int e4_ = csrL[u_ + 4], e5_ = csrL[u_ + 5], e6_ = csrL[u_ + 6], e7_ = csrL[u_ + 7]; \
    int p1_ = (slot & 1) ? e1_ : e0_, q1_ = (slot & 1) ? e3_ : e2_;            \
    int s1_ = (slot & 2) ? q1_ : p1_;                                          \
    int p2_ = (slot & 1) ? e5_ : e4_, q2_ = (slot & 1) ? e7_ : e6_;            \
    int s2_ = (slot & 2) ? q2_ : p2_;                                          \
    unsigned w1_ = xq[((unsigned)s1_ << 4) | q];                               \
    unsigned w2_ = xq[((unsigned)s2_ << 4) | q];                               \
    f32x2 l1_ = __builtin_amdgcn_cvt_pk_f32_fp8(w1_, false);                   \
    f32x2 h1_ = __builtin_amdgcn_cvt_pk_f32_fp8(w1_, true);                    \
    f32x2 l2_ = __builtin_amdgcn_cvt_pk_f32_fp8(w2_, false);                   \
    f32x2 h2_ = __builtin_amdgcn_cvt_pk_f32_fp8(w2_, true);                    \
    AL += l1_; AH += h1_; AL += l2_; AH += h2_;                                \
  }

// FUSED counting sort (CSR in LDS) + aggregation. SINGLE global pass:
// segments -> LDS stage (+hist) -> scan -> LDS scatter -> aggregate.
__global__ __launch_bounds__(512) void k_sortagg(
    const int* __restrict__ packed2, const int* __restrict__ cnt,
    const unsigned* __restrict__ xq, int* __restrict__ deg,
    __half* __restrict__ Sh, int FGRID, int N) {
  __shared__ int scnt[264];
  __shared__ int hist[NPB];
  __shared__ int sc[NPB];
  __shared__ int curs[NPB];
  __shared__ int stage[STAGECAP];
  __shared__ int csrL[CAPL];
  __shared__ int nstage_;
  int b = blockIdx.x, t = threadIdx.x;
  if (t < NPB) hist[t] = 0;
  if (t == 0) nstage_ = 0;
  for (int i = t; i < FGRID; i += 512) scnt[i] = cnt[(size_t)b * FGRID + i];
  __syncthreads();
  int slots = FGRID * SEGCAP;
  const int* seg = packed2 + (size_t)b * FGRID * SEGCAP;
  for (int idx = t; idx < slots; idx += 512) {
    int s = idx >> 5, k = idx & 31;
    if (k < scnt[s]) {
      int pk = seg[idx];
      int p = atomicAdd(&nstage_, 1);
      if (p < STAGECAP) {
        stage[p] = pk;
        atomicAdd(&hist[(pk >> 20) & 127], 1);
      }
    }
  }
  __syncthreads();
  int v = (t < NPB) ? hist[t] : 0;
  int pv = (v + 7) & ~7;       // padded degree
  if (t < NPB) sc[t] = pv;
  __syncthreads();
  for (int d = 1; d < NPB; d <<= 1) {
    int a = (t >= d && t < NPB) ? sc[t - d] : 0;
    __syncthreads();
    if (t < NPB) sc[t] += a;
    __syncthreads();
  }
  if (t < NPB) {
    int ex = sc[t] - pv;       // local CSR start
    curs[t] = ex;
    int n = b * NPB + t;
    if (n < N) deg[n] = v;
    for (int k = v; k < pv; ++k) csrL[ex + k] = N;  // pads -> zero row
  }
  __syncthreads();
  int tot = nstage_ < STAGECAP ? nstage_ : STAGECAP;
  for (int idx = t; idx < tot; idx += 512) {
    int pk = stage[idx];
    int p = atomicAdd(&curs[(pk >> 20) & 127], 1);
    csrL[p] = pk & 0xFFFFF;
  }
  __syncthreads();
  // ---- aggregation: wave w owns local nodes [w*16, w*16+16), dual-interleaved
  int w = t >> 6;
  unsigned lane = t & 63;
  unsigned q = lane & 15;          // feature quad
  int slot = (int)(lane >> 4);     // 0..3
  for (int p = 0; p < 16; p += 2) {
    int ln = w * 16 + p;
    int vA = hist[ln], vB = hist[ln + 1];
    int pdA = (vA + 7) & ~7, pdB = (vB + 7) & ~7;
    int j0A = sc[ln] - pdA, j0B = sc[ln + 1] - pdB;
    f32x2 aAL = {0.f, 0.f}, aAH = {0.f, 0.f};
    f32x2 aBL = {0.f, 0.f}, aBH = {0.f, 0.f};
    int jA = 0, jB = 0;
    for (; jA < pdA && jB < pdB; jA += 8, jB += 8) {
      LBATCH8(j0A, jA, aAL, aAH)
      LBATCH8(j0B, jB, aBL, aBH)
    }
    for (; jA < pdA; jA += 8) LBATCH8(j0A, jA, aAL, aAH)
    for (; jB < pdB; jB += 8) LBATCH8(j0B, jB, aBL, aBH)
    aAL.x += __shfl_xor(aAL.x, 16); aAL.y += __shfl_xor(aAL.y, 16);
    aAH.x += __shfl_xor(aAH.x, 16); aAH.y += __shfl_xor(aAH.y, 16);
    aAL.x += __shfl_xor(aAL.x, 32); aAL.y += __shfl_xor(aAL.y, 32);
    aAH.x += __shfl_xor(aAH.x, 32); aAH.y += __shfl_xor(aAH.y, 32);
    aBL.x += __shfl_xor(aBL.x, 16); aBL.y += __shfl_xor(aBL.y, 16);
    aBH.x += __shfl_xor(aBH.x, 16); aBH.y += __shfl_xor(aBH.y, 16);
    aBL.x += __shfl_xor(aBL.x, 32); aBL.y += __shfl_xor(aBL.y, 32);
    aBH.x += __shfl_xor(aBH.x, 32); aBH.y += __shfl_xor(aBH.y, 32);
    int n = b * NPB + ln;
    if (slot == 0) {
      if (n < N) {
        f16x4 o;
        o[0] = (_Float16)aAL.x; o[1] = (_Float16)aAL.y;
        o[2] = (_Float16)aAH.x; o[3] = (_Float16)aAH.y;
        *(f16x4*)(Sh + ((size_t)n << 6) + (q << 2)) = o;
      }
      if (n + 1 < N) {
        f16x4 o;
        o[0] = (_Float16)aBL.x; o[1] = (_Float16)aBL.y;
        o[2] = (_Float16)aBH.x; o[3] = (_Float16)aBH.y;
        *(f16x4*)(Sh + ((size_t)(n + 1) << 6) + (q << 2)) = o;
      }
    }
  }
}

// node model via MFMA + per-block stats partials (LDS reduce, non-atomic global write)
__global__ __launch_bounds__(256) void k_nodeM(const __half* __restrict__ xh,
    const __half* __restrict__ Sh, const int* __restrict__ deg,
    const __half* __restrict__ Wfrag, const float* __restrict__ c2,
    const float* __restrict__ bnode, const float* __restrict__ pa,
    __half* __restrict__ Hh, float* __restrict__ pstats, int N) {
  __shared__ float ls[128];
  const f16x8* WF = (const f16x8*)Wfrag;
  int t = threadIdx.x, lane = t & 63;
  if (t < 128) ls[t] = 0.f;
  f16x8 B[24];
#pragma unroll
  for (int f = 0; f < 24; ++f) B[f] = WF[f * 64 + lane];
  float slope = pa[0];
  int wid = (blockIdx.x * blockDim.x + t) >> 6;
  int nw = (gridDim.x * blockDim.x) >> 6;
  int ntile = N >> 4;
  int r = lane & 15, g = lane >> 4;
  float ws[4] = {0, 0, 0, 0}, wq[4] = {0, 0, 0, 0};
  __syncthreads();
  for (int tile = wid; tile < ntile; tile += nw) {
    int n0 = tile << 4;
    float dg[4];
#pragma unroll
    for (int qq = 0; qq < 4; ++qq) dg[qq] = (float)deg[n0 + g * 4 + qq];
    const f16x8* xp = (const f16x8*)(xh + (size_t)(n0 + r) * 64 + g * 8);
    const f16x8* sp = (const f16x8*)(Sh + (size_t)(n0 + r) * 64 + g * 8);
    f16x8 ax0 = xp[0], ax1 = xp[4];
    f16x8 as0 = sp[0], as1 = sp[4];
    f32x4 accA[4], accB[4];
#pragma unroll
    for (int ct = 0; ct < 4; ++ct) {
      f32x4 a = {0.f, 0.f, 0.f, 0.f};
      a = __builtin_amdgcn_mfma_f32_16x16x32_f16(ax0, B[0 + ct], a, 0, 0, 0);
      a = __builtin_amdgcn_mfma_f32_16x16x32_f16(ax1, B[4 + ct], a, 0, 0, 0);
      a = __builtin_amdgcn_mfma_f32_16x16x32_f16(as0, B[8 + ct], a, 0, 0, 0);
      a = __builtin_amdgcn_mfma_f32_16x16x32_f16(as1, B[12 + ct], a, 0, 0, 0);
      accA[ct] = a;
      f32x4 bb = {0.f, 0.f, 0.f, 0.f};
      bb = __builtin_amdgcn_mfma_f32_16x16x32_f16(ax0, B[16 + ct], bb, 0, 0, 0);
      bb = __builtin_amdgcn_mfma_f32_16x16x32_f16(ax1, B[20 + ct], bb, 0, 0, 0);
      accB[ct] = bb;
    }
#pragma unroll
    for (int ct = 0; ct < 4; ++ct) {
      int c = ct * 16 + r;
      float cc = c2[c], bv = bnode[c];
#pragma unroll
      for (int qq = 0; qq < 4; ++qq) {
        float hv = accA[ct][qq] + dg[qq] * (accB[ct][qq] + cc) + bv;
        hv = hv >= 0.f ? hv : slope * hv;
        ws[ct] += hv; wq[ct] += hv * hv;
        Hh[(size_t)(n0 + g * 4 + qq) * 64 + c] = __float2half_rn(hv);
      }
    }
  }
#pragma unroll
  for (int ct = 0; ct < 4; ++ct) {
    int c = ct * 16 + r;
    atomicAdd(&ls[c], ws[ct]);
    atomicAdd(&ls[64 + c], wq[ct]);
  }
  __syncthreads();
  if (t < 128) pstats[(size_t)blockIdx.x * 128 + t] = ls[t];
}

// reduce per-block partials (nb x 128) -> stats[128]
__global__ __launch_bounds__(256) void k_stats(const float* __restrict__ pstats,
    float* __restrict__ stats, int nb) {
  int t = threadIdx.x;
  int col = t & 127;
  int half = t >> 7;  // 0/1
  float acc = 0.f;
  for (int i = blockIdx.x * 2 + half; i < nb; i += gridDim.x * 2)
    acc += pstats[(size_t)i * 128 + col];
  atomicAdd(&stats[col], acc);
}

// BN finalize fused into the output pass
__global__ void k_out2(const __half2* __restrict__ hh, const float* __restrict__ stats,
                       const float* __restrict__ gamma, const float* __restrict__ beta,
                       float2* __restrict__ out2, int n2, float invN) {
  int i = blockIdx.x * blockDim.x + threadIdx.x;
  if (i < n2) {
    int cb = (i & 31) * 2;
    float m0 = stats[cb] * invN, m1 = stats[cb + 1] * invN;
    float v0 = stats[64 + cb] * invN - m0 * m0;
    float v1 = stats[64 + cb + 1] * invN - m1 * m1;
    float sc0 = gamma[cb] * rsqrtf(v0 + 1e-5f);
    float sc1 = gamma[cb + 1] * rsqrtf(v1 + 1e-5f);
    float sh0 = beta[cb] - m0 * sc0;
    float sh1 = beta[cb + 1] - m1 * sc1;
    __half2 v = hh[i];
    float2 o;
    o.x = __half2float(v.x) * sc0 + sh0;
    o.y = __half2float(v.y) * sc1 + sh1;
    out2[i] = o;
  }
}

// ---------------- launch ----------------

extern "C" void kernel_launch(void* const* d_in, const int* in_sizes, int n_in,
                              void* d_out, int out_size, void* d_ws, size_t ws_size,
                              hipStream_t stream) {
  const float* x     = (const float*)d_in[0];
  const int*   ei    = (const int*)d_in[1];
  const float* We    = (const float*)d_in[2];
  const float* be    = (const float*)d_in[3];
  const float* Wn    = (const float*)d_in[4];
  const float* bnode = (const float*)d_in[5];
  const float* pa    = (const float*)d_in[6];
  const float* gamma = (const float*)d_in[7];
  const float* beta  = (const float*)d_in[8];

  int N = in_sizes[0] / 64;
  int E = in_sizes[1] / 2;
  const int* srcA = ei;
  const int* dstA = ei + E;

  int NBUCK = (N + NPB - 1) / NPB;         // 782
  int FGRID = (E + FCHUNK - 1) / FCHUNK;   // 261

  char* ws = (char*)d_ws;
  size_t off = 0;
  auto alloc = [&](size_t bytes) -> void* {
    void* p = (void*)(ws + off);
    off += (bytes + 255) & ~(size_t)255;
    return p;
  };
  int ntile = N / 16;                       // 6250
  int mgrid = (ntile + 3) / 4;              // 1563 blocks -> 1 tile per wave

  float*    stats   = (float*)alloc(128 * 4);
  int*      cnt     = (int*)alloc((size_t)NBUCK * FGRID * 4);
  int*      packed2 = (int*)alloc((size_t)NBUCK * FGRID * SEGCAP * 4);  // 26 MB
  int*      deg     = (int*)alloc((size_t)N * 4);
  __half*   xh      = (__half*)alloc((size_t)(N + 1) * 64 * 2);  // +1 zero row
  unsigned* xq      = (unsigned*)alloc((size_t)(N + 1) * 64);    // fp8 table +1 zero row
  __half*   Sh      = (__half*)alloc((size_t)N * 64 * 2);
  __half*   Hh      = (__half*)alloc((size_t)N * 64 * 2);
  __half*   Wfrag   = (__half*)alloc((size_t)24 * 512 * 2);
  float*    c2      = (float*)alloc(64 * 4);
  float*    pstats  = (float*)alloc((size_t)mgrid * 128 * 4);

  int n4 = N * 16;
  int X2 = (n4 + 1023) / 1024;             // 1563
  int n2 = N * 32;
  int pgrid = FGRID + X2 + 25;             // 1849

  k_prepfill<<<pgrid, 1024, 0, stream>>>(
      (const float4*)x, (__half2*)xh, xq, n4, X2,
      srcA, dstA, cnt, packed2, E, FGRID,
      We, be, Wn, Wfrag, c2, stats, NBUCK, N);
  k_sortagg<<<NBUCK, 512, 0, stream>>>(packed2, cnt, xq, deg, Sh, FGRID, N);
  k_nodeM<<<mgrid, 256, 0, stream>>>(xh, Sh, deg, Wfrag, c2, bnode, pa, Hh, pstats, N);
  k_stats<<<64, 256, 0, stream>>>(pstats, stats, mgrid);
  k_out2<<<(n2 + 255) / 256, 256, 0, stream>>>((const __half2*)Hh, stats, gamma, beta,
                                               (float2*)d_out, n2, 1.0f / (float)N);
}

// Round 24
// 106.027 us; speedup vs baseline: 1.1262x; 1.0532x over previous
//
#include <hip/hip_runtime.h>
#include <hip/hip_fp16.h>

typedef _Float16 f16x8 __attribute__((ext_vector_type(8)));
typedef _Float16 f16x4 __attribute__((ext_vector_type(4)));
typedef float f32x4 __attribute__((ext_vector_type(4)));
typedef float f32x2 __attribute__((ext_vector_type(2)));

#define NPB 128      // nodes per bucket (dst >> 7)
#define FCHUNK 6144  // edges per fill block (6 per thread @ 1024 threads)
#define SEGCAP 32    // slots per (fill-block, bucket) segment (mean 7.9, +8.6sigma<32)
#define CAPL 3584    // LDS csr capacity per bucket (mean 2048+pads, 8sigma safe)
#define STAGECAP 4096 // LDS staging capacity (mean 2048, sigma 45)

// FUSED prep + fill. 1024-thread blocks, roles by blockIdx — FILL FIRST so its
// latency-bound blocks co-reside with BW-bound convert blocks (no fill tail):
//  [0,FGRID): edge fill | [FGRID,+X2): x fp32->{fp16,fp8} | +24 wfrag | last: misc
__global__ __launch_bounds__(1024) void k_prepfill(
    const float4* __restrict__ x4, __half2* __restrict__ xh2,
    unsigned* __restrict__ xq, int n4, int X2,
    const int* __restrict__ src, const int* __restrict__ dst,
    int* __restrict__ cnt, int* __restrict__ packed2, int E, int FGRID,
    const float* __restrict__ We, const float* __restrict__ be,
    const float* __restrict__ Wn, __half* __restrict__ Wfrag, float* __restrict__ c2,
    float* __restrict__ stats, int nbuck, int N) {
  int b = blockIdx.x, t = threadIdx.x;
  if (b < FGRID) {
    int fb = b;
    __shared__ int lh[1024];
    int e0 = fb * FCHUNK;
    int e1 = min(e0 + FCHUNK, E);
    lh[t] = 0;
    __syncthreads();
    int dv[6];
#pragma unroll
    for (int i = 0; i < 6; ++i) {
      int e = e0 + t + i * 1024;
      dv[i] = (e < e1) ? dst[e] : -1;
      if (dv[i] >= 0) atomicAdd(&lh[dv[i] >> 7], 1);
    }
    __syncthreads();
    if (t < nbuck) cnt[(size_t)t * FGRID + fb] = lh[t];  // non-atomic count
    lh[t] = 0;  // reuse as local cursor
    __syncthreads();
#pragma unroll
    for (int i = 0; i < 6; ++i) {
      int d = dv[i];
      if (d >= 0) {
        int e = e0 + t + i * 1024;
        int bk = d >> 7;
        unsigned lp = (unsigned)atomicAdd(&lh[bk], 1);
        if (lp < SEGCAP)
          packed2[((size_t)bk * FGRID + fb) * SEGCAP + lp] = src[e] | ((d & 127) << 20);
      }
    }
  } else if (b < FGRID + X2) {
    int i = (b - FGRID) * 1024 + t;
    if (i < n4) {
      float4 v = x4[i];
      __half2 a, c;
      a.x = __float2half_rn(v.x); a.y = __float2half_rn(v.y);
      c.x = __float2half_rn(v.z); c.y = __float2half_rn(v.w);
      xh2[2 * i] = a;
      xh2[2 * i + 1] = c;
      int w = __builtin_amdgcn_cvt_pk_fp8_f32(v.x, v.y, 0, false);
      w = __builtin_amdgcn_cvt_pk_fp8_f32(v.z, v.w, w, true);
      xq[i] = (unsigned)w;
    }
  } else if (b < FGRID + X2 + 24) {
    int mb = b - FGRID - X2;
    if (t < 512) {
      int mat = mb >> 3, kk = (mb >> 2) & 1, ct = mb & 3;
      int lane = t >> 3, j = t & 7;
      int k = kk * 32 + ((lane >> 4) & 3) * 8 + j;
      int col = ct * 16 + (lane & 15);
      float v;
      if (mat == 0) {
        v = Wn[k * 64 + col];
      } else if (mat == 1) {
        float a = 0.f;
        for (int m = 0; m < 64; ++m) a += We[k * 64 + m] * Wn[(64 + m) * 64 + col];
        v = a;
      } else {
        float a = 0.f;
        for (int m = 0; m < 64; ++m) a += We[(64 + k) * 64 + m] * Wn[(64 + m) * 64 + col];
        v = a;
      }
      Wfrag[mb * 512 + t] = __float2half_rn(v);
    }
  } else {
    if (t < 64) {
      float a = 0.f;
      for (int m = 0; m < 64; ++m) a += be[m] * Wn[(64 + m) * 64 + t];
      c2[t] = a;
    } else if (t < 96) {
      __half2 z; z.x = __float2half_rn(0.f); z.y = __float2half_rn(0.f);
      xh2[(size_t)N * 32 + (t - 64)] = z;   // zero fp16 row N
    } else if (t < 112) {
      xq[(size_t)N * 16 + (t - 96)] = 0u;   // zero fp8 row N (pad target)
    } else if (t >= 128 && t < 256) {
      stats[t - 128] = 0.f;
    }
  }
}

// one 8-edge batch: per-lane direct LDS index reads (slot-routed, no selects),
// 2 dword fp8 gathers (4 feats each), HW cvt, f32 accumulate.
// Edge order within a node is arbitrary -> slot assignment is free.
#define LBATCH8(J0, J, AL, AH)                                                 \
  {                                                                            \
    int u_ = (J0) + (J);                                                       \
    unsigned s1_ = (unsigned)csrL[u_ + slot];                                  \
    unsigned s2_ = (unsigned)csrL[u_ + 4 + slot];                              \
    unsigned w1_ = xq[(s1_ << 4) | q];                                         \
    unsigned w2_ = xq[(s2_ << 4) | q];                                         \
    f32x2 l1_ = __builtin_amdgcn_cvt_pk_f32_fp8(w1_, false);                   \
    f32x2 h1_ = __builtin_amdgcn_cvt_pk_f32_fp8(w1_, true);                    \
    f32x2 l2_ = __builtin_amdgcn_cvt_pk_f32_fp8(w2_, false);                   \
    f32x2 h2_ = __builtin_amdgcn_cvt_pk_f32_fp8(w2_, true);                    \
    AL += l1_; AH += h1_; AL += l2_; AH += h2_;                                \
  }

// FUSED counting sort (CSR in LDS) + aggregation. SINGLE global pass:
// segments -> LDS stage (+hist) -> scan -> LDS scatter -> aggregate.
__global__ __launch_bounds__(512) void k_sortagg(
    const int* __restrict__ packed2, const int* __restrict__ cnt,
    const unsigned* __restrict__ xq, int* __restrict__ deg,
    __half* __restrict__ Sh, int FGRID, int N) {
  __shared__ int scnt[264];
  __shared__ int hist[NPB];
  __shared__ int sc[NPB];
  __shared__ int curs[NPB];
  __shared__ int stage[STAGECAP];
  __shared__ int csrL[CAPL];
  __shared__ int nstage_;
  int b = blockIdx.x, t = threadIdx.x;
  if (t < NPB) hist[t] = 0;
  if (t == 0) nstage_ = 0;
  for (int i = t; i < FGRID; i += 512) scnt[i] = cnt[(size_t)b * FGRID + i];
  __syncthreads();
  int slots = FGRID * SEGCAP;
  const int* seg = packed2 + (size_t)b * FGRID * SEGCAP;
  for (int idx = t; idx < slots; idx += 512) {
    int s = idx >> 5, k = idx & 31;
    if (k < scnt[s]) {
      int pk = seg[idx];
      int p = atomicAdd(&nstage_, 1);
      if (p < STAGECAP) {
        stage[p] = pk;
        atomicAdd(&hist[(pk >> 20) & 127], 1);
      }
    }
  }
  __syncthreads();
  int v = (t < NPB) ? hist[t] : 0;
  int pv = (v + 7) & ~7;       // padded degree
  if (t < NPB) sc[t] = pv;
  __syncthreads();
  for (int d = 1; d < NPB; d <<= 1) {
    int a = (t >= d && t < NPB) ? sc[t - d] : 0;
    __syncthreads();
    if (t < NPB) sc[t] += a;
    __syncthreads();
  }
  if (t < NPB) {
    int ex = sc[t] - pv;       // local CSR start
    curs[t] = ex;
    int n = b * NPB + t;
    if (n < N) deg[n] = v;
    for (int k = v; k < pv; ++k) csrL[ex + k] = N;  // pads -> zero row
  }
  __syncthreads();
  int tot = nstage_ < STAGECAP ? nstage_ : STAGECAP;
  for (int idx = t; idx < tot; idx += 512) {
    int pk = stage[idx];
    int p = atomicAdd(&curs[(pk >> 20) & 127], 1);
    csrL[p] = pk & 0xFFFFF;
  }
  __syncthreads();
  // ---- aggregation: wave w owns local nodes [w*16, w*16+16), dual-interleaved
  int w = t >> 6;
  unsigned lane = t & 63;
  unsigned q = lane & 15;          // feature quad
  int slot = (int)(lane >> 4);     // 0..3
  for (int p = 0; p < 16; p += 2) {
    int ln = w * 16 + p;
    int vA = hist[ln], vB = hist[ln + 1];
    int pdA = (vA + 7) & ~7, pdB = (vB + 7) & ~7;
    int j0A = sc[ln] - pdA, j0B = sc[ln + 1] - pdB;
    f32x2 aAL = {0.f, 0.f}, aAH = {0.f, 0.f};
    f32x2 aBL = {0.f, 0.f}, aBH = {0.f, 0.f};
    int jA = 0, jB = 0;
    for (; jA < pdA && jB < pdB; jA += 8, jB += 8) {
      LBATCH8(j0A, jA, aAL, aAH)
      LBATCH8(j0B, jB, aBL, aBH)
    }
    for (; jA < pdA; jA += 8) LBATCH8(j0A, jA, aAL, aAH)
    for (; jB < pdB; jB += 8) LBATCH8(j0B, jB, aBL, aBH)
    aAL.x += __shfl_xor(aAL.x, 16); aAL.y += __shfl_xor(aAL.y, 16);
    aAH.x += __shfl_xor(aAH.x, 16); aAH.y += __shfl_xor(aAH.y, 16);
    aAL.x += __shfl_xor(aAL.x, 32); aAL.y += __shfl_xor(aAL.y, 32);
    aAH.x += __shfl_xor(aAH.x, 32); aAH.y += __shfl_xor(aAH.y, 32);
    aBL.x += __shfl_xor(aBL.x, 16); aBL.y += __shfl_xor(aBL.y, 16);
    aBH.x += __shfl_xor(aBH.x, 16); aBH.y += __shfl_xor(aBH.y, 16);
    aBL.x += __shfl_xor(aBL.x, 32); aBL.y += __shfl_xor(aBL.y, 32);
    aBH.x += __shfl_xor(aBH.x, 32); aBH.y += __shfl_xor(aBH.y, 32);
    int n = b * NPB + ln;
    if (slot == 0) {
      if (n < N) {
        f16x4 o;
        o[0] = (_Float16)aAL.x; o[1] = (_Float16)aAL.y;
        o[2] = (_Float16)aAH.x; o[3] = (_Float16)aAH.y;
        *(f16x4*)(Sh + ((size_t)n << 6) + (q << 2)) = o;
      }
      if (n + 1 < N) {
        f16x4 o;
        o[0] = (_Float16)aBL.x; o[1] = (_Float16)aBL.y;
        o[2] = (_Float16)aBH.x; o[3] = (_Float16)aBH.y;
        *(f16x4*)(Sh + ((size_t)(n + 1) << 6) + (q << 2)) = o;
      }
    }
  }
}

// node model via MFMA + per-block stats partials (LDS reduce, non-atomic global write)
__global__ __launch_bounds__(256) void k_nodeM(const __half* __restrict__ xh,
    const __half* __restrict__ Sh, const int* __restrict__ deg,
    const __half* __restrict__ Wfrag, const float* __restrict__ c2,
    const float* __restrict__ bnode, const float* __restrict__ pa,
    __half* __restrict__ Hh, float* __restrict__ pstats, int N) {
  __shared__ float ls[128];
  const f16x8* WF = (const f16x8*)Wfrag;
  int t = threadIdx.x, lane = t & 63;
  if (t < 128) ls[t] = 0.f;
  f16x8 B[24];
#pragma unroll
  for (int f = 0; f < 24; ++f) B[f] = WF[f * 64 + lane];
  float slope = pa[0];
  int wid = (blockIdx.x * blockDim.x + t) >> 6;
  int nw = (gridDim.x * blockDim.x) >> 6;
  int ntile = N >> 4;
  int r = lane & 15, g = lane >> 4;
  float ws[4] = {0, 0, 0, 0}, wq[4] = {0, 0, 0, 0};
  __syncthreads();
  for (int tile = wid; tile < ntile; tile += nw) {
    int n0 = tile << 4;
    float dg[4];
#pragma unroll
    for (int qq = 0; qq < 4; ++qq) dg[qq] = (float)deg[n0 + g * 4 + qq];
    const f16x8* xp = (const f16x8*)(xh + (size_t)(n0 + r) * 64 + g * 8);
    const f16x8* sp = (const f16x8*)(Sh + (size_t)(n0 + r) * 64 + g * 8);
    f16x8 ax0 = xp[0], ax1 = xp[4];
    f16x8 as0 = sp[0], as1 = sp[4];
    f32x4 accA[4], accB[4];
#pragma unroll
    for (int ct = 0; ct < 4; ++ct) {
      f32x4 a = {0.f, 0.f, 0.f, 0.f};
      a = __builtin_amdgcn_mfma_f32_16x16x32_f16(ax0, B[0 + ct], a, 0, 0, 0);
      a = __builtin_amdgcn_mfma_f32_16x16x32_f16(ax1, B[4 + ct], a, 0, 0, 0);
      a = __builtin_amdgcn_mfma_f32_16x16x32_f16(as0, B[8 + ct], a, 0, 0, 0);
      a = __builtin_amdgcn_mfma_f32_16x16x32_f16(as1, B[12 + ct], a, 0, 0, 0);
      accA[ct] = a;
      f32x4 bb = {0.f, 0.f, 0.f, 0.f};
      bb = __builtin_amdgcn_mfma_f32_16x16x32_f16(ax0, B[16 + ct], bb, 0, 0, 0);
      bb = __builtin_amdgcn_mfma_f32_16x16x32_f16(ax1, B[20 + ct], bb, 0, 0, 0);
      accB[ct] = bb;
    }
#pragma unroll
    for (int ct = 0; ct < 4; ++ct) {
      int c = ct * 16 + r;
      float cc = c2[c], bv = bnode[c];
#pragma unroll
      for (int qq = 0; qq < 4; ++qq) {
        float hv = accA[ct][qq] + dg[qq] * (accB[ct][qq] + cc) + bv;
        hv = hv >= 0.f ? hv : slope * hv;
        ws[ct] += hv; wq[ct] += hv * hv;
        Hh[(size_t)(n0 + g * 4 + qq) * 64 + c] = __float2half_rn(hv);
      }
    }
  }
#pragma unroll
  for (int ct = 0; ct < 4; ++ct) {
    int c = ct * 16 + r;
    atomicAdd(&ls[c], ws[ct]);
    atomicAdd(&ls[64 + c], wq[ct]);
  }
  __syncthreads();
  if (t < 128) pstats[(size_t)blockIdx.x * 128 + t] = ls[t];
}

// reduce per-block partials (nb x 128) -> stats[128]
__global__ __launch_bounds__(256) void k_stats(const float* __restrict__ pstats,
    float* __restrict__ stats, int nb) {
  int t = threadIdx.x;
  int col = t & 127;
  int half = t >> 7;  // 0/1
  float acc = 0.f;
  for (int i = blockIdx.x * 2 + half; i < nb; i += gridDim.x * 2)
    acc += pstats[(size_t)i * 128 + col];
  atomicAdd(&stats[col], acc);
}

// BN finalize fused into the output pass
__global__ void k_out2(const __half2* __restrict__ hh, const float* __restrict__ stats,
                       const float* __restrict__ gamma, const float* __restrict__ beta,
                       float2* __restrict__ out2, int n2, float invN) {
  int i = blockIdx.x * blockDim.x + threadIdx.x;
  if (i < n2) {
    int cb = (i & 31) * 2;
    float m0 = stats[cb] * invN, m1 = stats[cb + 1] * invN;
    float v0 = stats[64 + cb] * invN - m0 * m0;
    float v1 = stats[64 + cb + 1] * invN - m1 * m1;
    float sc0 = gamma[cb] * rsqrtf(v0 + 1e-5f);
    float sc1 = gamma[cb + 1] * rsqrtf(v1 + 1e-5f);
    float sh0 = beta[cb] - m0 * sc0;
    float sh1 = beta[cb + 1] - m1 * sc1;
    __half2 v = hh[i];
    float2 o;
    o.x = __half2float(v.x) * sc0 + sh0;
    o.y = __half2float(v.y) * sc1 + sh1;
    out2[i] = o;
  }
}

// ---------------- launch ----------------

extern "C" void kernel_launch(void* const* d_in, const int* in_sizes, int n_in,
                              void* d_out, int out_size, void* d_ws, size_t ws_size,
                              hipStream_t stream) {
  const float* x     = (const float*)d_in[0];
  const int*   ei    = (const int*)d_in[1];
  const float* We    = (const float*)d_in[2];
  const float* be    = (const float*)d_in[3];
  const float* Wn    = (const float*)d_in[4];
  const float* bnode = (const float*)d_in[5];
  const float* pa    = (const float*)d_in[6];
  const float* gamma = (const float*)d_in[7];
  const float* beta  = (const float*)d_in[8];

  int N = in_sizes[0] / 64;
  int E = in_sizes[1] / 2;
  const int* srcA = ei;
  const int* dstA = ei + E;

  int NBUCK = (N + NPB - 1) / NPB;         // 782
  int FGRID = (E + FCHUNK - 1) / FCHUNK;   // 261

  char* ws = (char*)d_ws;
  size_t off = 0;
  auto alloc = [&](size_t bytes) -> void* {
    void* p = (void*)(ws + off);
    off += (bytes + 255) & ~(size_t)255;
    return p;
  };
  int ntile = N / 16;                       // 6250
  int mgrid = (ntile + 3) / 4;              // 1563 blocks -> 1 tile per wave

  float*    stats   = (float*)alloc(128 * 4);
  int*      cnt     = (int*)alloc((size_t)NBUCK * FGRID * 4);
  int*      packed2 = (int*)alloc((size_t)NBUCK * FGRID * SEGCAP * 4);  // 26 MB
  int*      deg     = (int*)alloc((size_t)N * 4);
  __half*   xh      = (__half*)alloc((size_t)(N + 1) * 64 * 2);  // +1 zero row
  unsigned* xq      = (unsigned*)alloc((size_t)(N + 1) * 64);    // fp8 table +1 zero row
  __half*   Sh      = (__half*)alloc((size_t)N * 64 * 2);
  __half*   Hh      = (__half*)alloc((size_t)N * 64 * 2);
  __half*   Wfrag   = (__half*)alloc((size_t)24 * 512 * 2);
  float*    c2      = (float*)alloc(64 * 4);
  float*    pstats  = (float*)alloc((size_t)mgrid * 128 * 4);

  int n4 = N * 16;
  int X2 = (n4 + 1023) / 1024;             // 1563
  int n2 = N * 32;
  int pgrid = FGRID + X2 + 25;             // 1849

  k_prepfill<<<pgrid, 1024, 0, stream>>>(
      (const float4*)x, (__half2*)xh, xq, n4, X2,
      srcA, dstA, cnt, packed2, E, FGRID,
      We, be, Wn, Wfrag, c2, stats, NBUCK, N);
  k_sortagg<<<NBUCK, 512, 0, stream>>>(packed2, cnt, xq, deg, Sh, FGRID, N);
  k_nodeM<<<mgrid, 256, 0, stream>>>(xh, Sh, deg, Wfrag, c2, bnode, pa, Hh, pstats, N);
  k_stats<<<64, 256, 0, stream>>>(pstats, stats, mgrid);
  k_out2<<<(n2 + 255) / 256, 256, 0, stream>>>((const __half2*)Hh, stats, gamma, beta,
                                               (float2*)d_out, n2, 1.0f / (float)N);
}